// Round 16
// baseline (192.510 us; speedup 1.0000x reference)
//
#include <hip/hip_runtime.h>

#define ALPHA 0.2f
#define EPSV 1e-8f
#define BUCK_BITS 8               // 256 srcs per bucket
#define BUCK (1 << BUCK_BITS)
#define CAP 5120                  // mean 4092, sigma ~64 -> +16 sigma
#define EPB_A 4096                // edges per binA block
#define EPT_A (EPB_A / 256)       // 16 edges per thread, register-buffered

typedef float f32x4 __attribute__((ext_vector_type(4)));
typedef short bf16x8 __attribute__((ext_vector_type(8)));

static __device__ __forceinline__ unsigned short f2bf(float f) {
    union { float f; unsigned int u; } c; c.f = f;
    unsigned int u = c.u;
    unsigned int round = ((u >> 16) & 1) + 0x7FFF;
    return (unsigned short)((u + round) >> 16);
}
static __device__ __forceinline__ float bflo(unsigned int u) {
    union { unsigned int u; float f; } c; c.u = u << 16; return c.f;
}
static __device__ __forceinline__ float bfhi(unsigned int u) {
    union { unsigned int u; float f; } c; c.u = u & 0xFFFF0000u; return c.f;
}

// ---------------------------------------------------------------------------
// Fused prep kernel, role-split by blockIdx:
//   [0, binBlocks)                : binA  — coarse-bin edges (latency-bound,
//                                   started first so it overlaps convX's BW work)
//   [binBlocks, binBlocks+32)     : convB — Wr -> Bp bf16 MFMA-B layout
//   [binBlocks+32, ... )          : convX — X f32 -> Ap bf16 MFMA-A layout,
//                                   via LDS transpose so BOTH the X read and
//                                   the Ap write are fully coalesced (r13's
//                                   convX was request-bound on its strided
//                                   X read: lanes strode 1KB).
// Ap unit (rt*32+kb)*16+i holds X[rt*16+i][kb*8..kb*8+7]; Ap aliases d_out.
// ---------------------------------------------------------------------------
__global__ __launch_bounds__(256) void prep_kernel(
    const float* __restrict__ X, uint4* __restrict__ Ap,
    const float* __restrict__ Wr, uint4* __restrict__ Bp,
    const int* __restrict__ adj_pos, const int* __restrict__ adj_neg,
    int* __restrict__ bucketCount, unsigned int* __restrict__ edges_tmp,
    int N, int E, int binBlocks)
{
    __shared__ char smem[64 * 256 * 2];     // 32 KB, overlaid per role
    const int tid = threadIdx.x;

    if ((int)blockIdx.x < binBlocks) {
        // ---- binA role ----
        int* hist = (int*)smem;
        int* base = hist + 512;
        int* cur  = base + 512;
        const int bb = blockIdx.x;
        const long long e0 = (long long)bb * EPB_A;
        const long long twoE = 2LL * E;

        hist[tid] = 0;
        hist[tid + 256] = 0;

        int esrc[EPT_A];
        unsigned int erec[EPT_A];
        #pragma unroll
        for (int k = 0; k < EPT_A; ++k) {
            const long long idx = e0 + (long long)k * 256 + tid;
            if (idx < twoE) {
                const int rel = (idx >= E) ? 1 : 0;
                const long long eidx = rel ? idx - E : idx;
                const int* __restrict__ adj = rel ? adj_neg : adj_pos;
                const int src = adj[eidx];
                const int dst = adj[E + eidx];
                esrc[k] = src;
                erec[k] = (unsigned int)dst | ((unsigned int)rel << 17) |
                          ((unsigned int)(src & (BUCK - 1)) << 18);
            } else {
                esrc[k] = -1;
            }
        }
        __syncthreads();

        #pragma unroll
        for (int k = 0; k < EPT_A; ++k)
            if (esrc[k] >= 0) atomicAdd(&hist[esrc[k] >> BUCK_BITS], 1);
        __syncthreads();

        {
            const int rot = (bb * 61) & 511;
            #pragma unroll
            for (int q = 0; q < 2; ++q) {
                const int t2 = (tid + q * 256 + rot) & 511;
                const int hv = hist[t2];
                base[t2] = hv ? atomicAdd(&bucketCount[t2], hv) : 0;
                cur[t2] = 0;
            }
        }
        __syncthreads();

        #pragma unroll
        for (int k = 0; k < EPT_A; ++k) {
            if (esrc[k] >= 0) {
                const int b = esrc[k] >> BUCK_BITS;
                const int r = atomicAdd(&cur[b], 1);
                const int pos = base[b] + r;
                if (pos < CAP)
                    edges_tmp[(size_t)b * CAP + pos] = erec[k];
            }
        }
        return;
    }

    if ((int)blockIdx.x < binBlocks + 32) {
        // ---- convB role ----
        const int t = (blockIdx.x - binBlocks) * 256 + tid;
        const int kb  = t >> 8;
        const int col = t & 255;
        const int rel = col >> 7;
        const int cc  = col & 127;
        unsigned short v[8];
        #pragma unroll
        for (int jj = 0; jj < 8; ++jj) {
            const int k = kb * 8 + jj;
            v[jj] = f2bf(Wr[(size_t)rel * 256 * 128 + (size_t)k * 128 + cc]);
        }
        Bp[t] = *reinterpret_cast<const uint4*>(v);
        return;
    }

    // ---- convX role: 64-row tile, LDS transpose ----
    unsigned short* T = (unsigned short*)smem;      // [64][256] swizzled
    const int cb = blockIdx.x - binBlocks - 32;
    const int tile0 = cb * 64;
    const float4* __restrict__ X4 = (const float4*)X;

    // read phase: wave reads one full row (1KB) per pass -> coalesced
    #pragma unroll
    for (int p = 0; p < 16; ++p) {
        const int f  = p * 256 + tid;       // float4 index in 64x64 grid
        const int r  = f >> 6;              // local row 0..63
        const int c4 = f & 63;              // float4 within row
        const int row = tile0 + r;
        float4 v4 = make_float4(0.f, 0.f, 0.f, 0.f);
        if (row < N) v4 = X4[(size_t)row * 64 + c4];
        unsigned short v[4];
        v[0] = f2bf(v4.x); v[1] = f2bf(v4.y); v[2] = f2bf(v4.z); v[3] = f2bf(v4.w);
        const int kbu  = c4 >> 1;           // 16B unit 0..31
        const int half = c4 & 1;
        const int su   = kbu ^ (r & 7);     // XOR swizzle
        *reinterpret_cast<uint2*>(&T[r * 256 + su * 8 + half * 4]) =
            *reinterpret_cast<const uint2*>(v);
    }
    __syncthreads();

    // write phase: consecutive Ap units per lane -> coalesced 16B stores
    #pragma unroll
    for (int q = 0; q < 8; ++q) {
        const int u    = q * 256 + tid;     // unit within tile, 0..2047
        const int rt_l = u >> 9;            // local 16-row tile 0..3
        const int kb   = (u >> 4) & 31;
        const int i    = u & 15;
        const int row_l = rt_l * 16 + i;
        const int grow  = tile0 + row_l;
        if (grow < N) {
            const int su = kb ^ (row_l & 7);
            Ap[((size_t)(tile0 >> 4) + rt_l) * 512 + (size_t)kb * 16 + i] =
                *reinterpret_cast<const uint4*>(&T[row_l * 256 + su * 8]);
        }
    }
}

// ---------------------------------------------------------------------------
// MFMA GEMM from pre-packed A (r11's form — the fast config: one coalesced
// 16B A-load per tile per kc, B from L2, no LDS/barriers, low VGPR).
// Block = 4 waves (wm = row-pair, wn = relation). Grid = ceil(N/64).
// ---------------------------------------------------------------------------
__global__ __launch_bounds__(256) void mfma_gemm_kernel(
    const uint4* __restrict__ Ap, const uint4* __restrict__ Bp,
    const float* __restrict__ ee, const float* __restrict__ a,
    unsigned short* __restrict__ h, float* __restrict__ sd, int N)
{
    const int tid  = threadIdx.x;
    const int lane = tid & 63;
    const int w    = tid >> 6;
    const int wm   = w >> 1;
    const int wn   = w & 1;
    const int rtb  = blockIdx.x * 4 + wm * 2;
    const int cl   = lane & 15;
    const int g    = lane >> 4;

    f32x4 acc[2][8];
    #pragma unroll
    for (int p = 0; p < 2; ++p)
        #pragma unroll
        for (int ct = 0; ct < 8; ++ct)
            acc[p][ct] = (f32x4){0.f, 0.f, 0.f, 0.f};

    const bool ld0 = (rtb + 1) * 16 <= N;
    const bool ld1 = (rtb + 2) * 16 <= N;
    const bf16x8 zf = (bf16x8){0,0,0,0,0,0,0,0};

    #pragma unroll
    for (int kc = 0; kc < 8; ++kc) {
        bf16x8 af[2], bfr[8];
        af[0] = ld0 ? *reinterpret_cast<const bf16x8*>(
            Ap + ((size_t)rtb * 32 + kc * 4) * 16 + lane) : zf;
        af[1] = ld1 ? *reinterpret_cast<const bf16x8*>(
            Ap + ((size_t)(rtb + 1) * 32 + kc * 4) * 16 + lane) : zf;
        #pragma unroll
        for (int ct = 0; ct < 8; ++ct) {
            const int kb  = kc * 4 + g;
            const int col = wn * 128 + ct * 16 + cl;
            bfr[ct] = *reinterpret_cast<const bf16x8*>(Bp + kb * 256 + col);
        }
        #pragma unroll
        for (int ct = 0; ct < 8; ++ct)
            acc[0][ct] = __builtin_amdgcn_mfma_f32_16x16x32_bf16(
                af[0], bfr[ct], acc[0][ct], 0, 0, 0);
        #pragma unroll
        for (int ct = 0; ct < 8; ++ct)
            acc[1][ct] = __builtin_amdgcn_mfma_f32_16x16x32_bf16(
                af[1], bfr[ct], acc[1][ct], 0, 0, 0);
    }

    float eev[8], asv[8], adv[8];
    #pragma unroll
    for (int ct = 0; ct < 8; ++ct) {
        const int col = wn * 128 + ct * 16 + cl;
        const int cc  = col & 127;
        eev[ct] = ee[col];
        asv[ct] = a[cc];
        adv[ct] = a[128 + cc];
    }

    float s_acc[2][4], d_acc[2][4];
    #pragma unroll
    for (int p = 0; p < 2; ++p) {
        #pragma unroll
        for (int reg = 0; reg < 4; ++reg) {
            const int row = (rtb + p) * 16 + g * 4 + reg;
            const bool ok = row < N;
            float sp = 0.f, dp = 0.f;
            #pragma unroll
            for (int ct = 0; ct < 8; ++ct) {
                const float v = acc[p][ct][reg] * eev[ct];
                sp += v * asv[ct];
                dp += v * adv[ct];
                if (ok) {
                    const int cc = ct * 16 + cl;
                    h[((size_t)wn * N + row) * 128 + cc] = f2bf(v);
                }
            }
            s_acc[p][reg] = sp;
            d_acc[p][reg] = dp;
        }
    }
    #pragma unroll
    for (int p = 0; p < 2; ++p)
        #pragma unroll
        for (int reg = 0; reg < 4; ++reg) {
            float sp = s_acc[p][reg], dp = d_acc[p][reg];
            #pragma unroll
            for (int off = 1; off < 16; off <<= 1) {
                sp += __shfl_xor(sp, off);
                dp += __shfl_xor(dp, off);
            }
            if (cl == 0) {
                const int row = (rtb + p) * 16 + g * 4 + reg;
                if (row < N) {
                    sd[(size_t)wn * 2 * N + row]     = sp;
                    sd[(size_t)wn * 2 * N + N + row] = dp;
                }
            }
        }
}

// ---------------------------------------------------------------------------
// sortB: one 512-thread block per bucket. LDS histogram -> scan -> rowBeg/End
// -> placement with e computed here; per-src row_sum in LDS -> rowSum.
// ---------------------------------------------------------------------------
__global__ __launch_bounds__(512) void sortB_kernel(
    const int* __restrict__ bucketCount, const unsigned int* __restrict__ edges_tmp,
    const float* __restrict__ sd,
    uint2* __restrict__ edges_final,
    int* __restrict__ rowBeg, int* __restrict__ rowEnd,
    float* __restrict__ rowSum, int N)
{
    __shared__ int hist[BUCK];
    __shared__ int cur[BUCK];
    __shared__ int ssum[BUCK];
    __shared__ float sSrc[2][BUCK];
    __shared__ float rsLds[BUCK];
    const int tid = threadIdx.x;          // 0..511
    const int b   = blockIdx.x;
    const int s0  = b << BUCK_BITS;
    const size_t tb = (size_t)b * CAP;
    const int cnt = min(bucketCount[b], CAP);

    if (tid < BUCK) {
        hist[tid] = 0;
        rsLds[tid] = 0.f;
        const int gsrc = s0 + tid;
        sSrc[0][tid] = (gsrc < N) ? sd[gsrc] : 0.f;
        sSrc[1][tid] = (gsrc < N) ? sd[2 * (size_t)N + gsrc] : 0.f;
    }
    __syncthreads();
    for (int j = tid; j < cnt; j += 512)
        atomicAdd(&hist[edges_tmp[tb + j] >> 18], 1);
    __syncthreads();

    int h0 = 0, incl = 0;
    if (tid < BUCK) { h0 = hist[tid]; ssum[tid] = h0; incl = h0; }
    __syncthreads();
    for (int off = 1; off < BUCK; off <<= 1) {
        const int u = (tid < BUCK && tid >= off) ? ssum[tid - off] : 0;
        __syncthreads();
        if (tid < BUCK) { incl += u; ssum[tid] = incl; }
        __syncthreads();
    }
    if (tid < BUCK) {
        const int excl = incl - h0;
        cur[tid] = excl;
        const int gidx = s0 + tid;
        if (gidx < N) {
            rowBeg[gidx] = (int)tb + excl;
            rowEnd[gidx] = (int)tb + incl;
        }
    }
    __syncthreads();
    for (int j = tid; j < cnt; j += 512) {
        const unsigned int r = edges_tmp[tb + j];
        const int sl  = r >> 18;
        const int rel = (r >> 17) & 1;
        const int dst = r & 0x1FFFF;
        float z = sSrc[rel][sl] + sd[(size_t)rel * 2 * N + N + dst];
        z = z > 0.f ? z : ALPHA * z;
        const float ev = 1.f / (1.f + __expf(-z));
        const int pos = atomicAdd(&cur[sl], 1);
        atomicAdd(&rsLds[sl], ev);
        edges_final[tb + pos] =
            make_uint2((unsigned int)(rel * N + dst), __float_as_uint(ev));
    }
    __syncthreads();
    if (tid < BUCK) {
        const int gidx = s0 + tid;
        if (gidx < N) rowSum[gidx] = rsLds[tid];
    }
}

// ---------------------------------------------------------------------------
// Gather: one wave per node; 8-deep unrolled; 32-bit byte offsets into h;
// row_sum precomputed in sortB.
// ---------------------------------------------------------------------------
__global__ __launch_bounds__(256) void gather_kernel(
    const int* __restrict__ rowBeg, const int* __restrict__ rowEnd,
    const float* __restrict__ rowSum,
    const uint2* __restrict__ edges,
    const unsigned short* __restrict__ h,
    const float* __restrict__ bias, float* __restrict__ out, int N)
{
    const long long gw = ((long long)blockIdx.x * blockDim.x + threadIdx.x) >> 6;
    const int lane = threadIdx.x & 63;
    if (gw >= N) return;
    const int n = (int)gw;

    const int beg = rowBeg[n];
    const int end = rowEnd[n];
    const unsigned loff = (unsigned)(lane << 2);
    const char* __restrict__ hb = (const char*)h;

    float ax = 0.f, ay = 0.f;
    int j = beg;
    for (; j + 8 <= end; j += 8) {
        uint2 r[8];
        #pragma unroll
        for (int k = 0; k < 8; ++k) r[k] = edges[j + k];
        unsigned int hv[8];
        #pragma unroll
        for (int k = 0; k < 8; ++k)
            hv[k] = *reinterpret_cast<const unsigned int*>(
                hb + ((r[k].x << 8) + loff));
        #pragma unroll
        for (int k = 0; k < 8; ++k) {
            const float e = __uint_as_float(r[k].y);
            ax += e * bflo(hv[k]);
            ay += e * bfhi(hv[k]);
        }
    }
    for (; j + 4 <= end; j += 4) {
        uint2 r[4];
        #pragma unroll
        for (int k = 0; k < 4; ++k) r[k] = edges[j + k];
        unsigned int hv[4];
        #pragma unroll
        for (int k = 0; k < 4; ++k)
            hv[k] = *reinterpret_cast<const unsigned int*>(
                hb + ((r[k].x << 8) + loff));
        #pragma unroll
        for (int k = 0; k < 4; ++k) {
            const float e = __uint_as_float(r[k].y);
            ax += e * bflo(hv[k]);
            ay += e * bfhi(hv[k]);
        }
    }
    for (; j < end; ++j) {
        const uint2 r = edges[j];
        const unsigned int hv = *reinterpret_cast<const unsigned int*>(
            hb + ((r.x << 8) + loff));
        const float e = __uint_as_float(r.y);
        ax += e * bflo(hv);
        ay += e * bfhi(hv);
    }
    const float inv = 1.f / (rowSum[n] + EPSV);
    const float2 bv = *reinterpret_cast<const float2*>(&bias[lane * 2]);
    float2 o;
    o.x = ax * inv + bv.x;
    o.y = ay * inv + bv.y;
    *reinterpret_cast<float2*>(&out[(size_t)n * 128 + lane * 2]) = o;
}

extern "C" void kernel_launch(void* const* d_in, const int* in_sizes, int n_in,
                              void* d_out, int out_size, void* d_ws, size_t ws_size,
                              hipStream_t stream) {
    const float* X      = (const float*)d_in[0];   // N x 256
    const float* ee     = (const float*)d_in[1];   // 2 x 128
    const float* Wr     = (const float*)d_in[2];   // 2 x 256 x 128
    const float* a      = (const float*)d_in[3];   // 1 x 256
    const float* bias   = (const float*)d_in[4];   // 1 x 128
    const int* adj_pos  = (const int*)d_in[5];     // 2 x E
    const int* adj_neg  = (const int*)d_in[6];     // 2 x E

    const int N = in_sizes[0] / 256;
    const int E = in_sizes[5] / 2;
    const int twoE = 2 * E;
    float* out = (float*)d_out;

    const int gemmBlocks = (N + 63) / 64;
    const int NBUCK = (N + BUCK - 1) >> BUCK_BITS;
    const int binBlocks  = (twoE + EPB_A - 1) / EPB_A;
    const int convBlocks = (N + 63) / 64;          // 64-row convX tiles

    // Ap aliases d_out (N*512 bytes == out_size*4); gather rewrites it last.
    uint4* Ap = (uint4*)d_out;

    // workspace layout
    char* ws = (char*)d_ws;
    uint4* Bp = (uint4*)ws;
    char* p = ws + 32 * 256 * 16;                               // 128 KB
    unsigned short* h = (unsigned short*)p; p += (size_t)2 * N * 128 * 2; // 51.2 MB
    float* sd         = (float*)p;  p += (size_t)4 * N * 4;
    int* bucketCount  = (int*)p;    p += 512 * 4;
    int* rowBeg       = (int*)p;    p += (size_t)N * 4;
    int* rowEnd       = (int*)p;    p += (size_t)N * 4;
    float* rowSum     = (float*)p;  p += (size_t)N * 4;
    p = (char*)(((uintptr_t)p + 15) & ~(uintptr_t)15);
    unsigned int* edges_tmp = (unsigned int*)p; p += (size_t)NBUCK * CAP * 4; // 8 MB
    uint2* edges_final = (uint2*)p; p += (size_t)NBUCK * CAP * 8;            // 16 MB

    (void)hipMemsetAsync(bucketCount, 0, 512 * sizeof(int), stream);

    prep_kernel<<<binBlocks + 32 + convBlocks, 256, 0, stream>>>(
        X, Ap, Wr, Bp, adj_pos, adj_neg, bucketCount, edges_tmp, N, E, binBlocks);

    mfma_gemm_kernel<<<gemmBlocks, 256, 0, stream>>>(Ap, Bp, ee, a, h, sd, N);

    sortB_kernel<<<NBUCK, 512, 0, stream>>>(
        bucketCount, edges_tmp, sd, edges_final, rowBeg, rowEnd, rowSum, N);

    gather_kernel<<<(int)(((long long)N * 64 + 255) / 256), 256, 0, stream>>>(
        rowBeg, rowEnd, rowSum, edges_final, (const unsigned short*)h, bias, out, N);
}

// Round 17
// 171.384 us; speedup vs baseline: 1.1233x; 1.1233x over previous
//
#include <hip/hip_runtime.h>

#define ALPHA 0.2f
#define EPSV 1e-8f
#define BUCK_BITS 8               // 256 srcs per bucket
#define BUCK (1 << BUCK_BITS)
#define CAP 5120                  // mean 4092, sigma ~64 -> +16 sigma
#define EPB_A 4096                // edges per binA block
#define EPT_A (EPB_A / 256)       // 16 edges per thread, register-buffered

typedef float f32x4 __attribute__((ext_vector_type(4)));
typedef short bf16x8 __attribute__((ext_vector_type(8)));

static __device__ __forceinline__ unsigned short f2bf(float f) {
    union { float f; unsigned int u; } c; c.f = f;
    unsigned int u = c.u;
    unsigned int round = ((u >> 16) & 1) + 0x7FFF;
    return (unsigned short)((u + round) >> 16);
}
static __device__ __forceinline__ float bflo(unsigned int u) {
    union { unsigned int u; float f; } c; c.u = u << 16; return c.f;
}
static __device__ __forceinline__ float bfhi(unsigned int u) {
    union { unsigned int u; float f; } c; c.u = u & 0xFFFF0000u; return c.f;
}

// ---------------------------------------------------------------------------
// Fused convB + binA (block-range split) — unchanged from r14 (the best
// measured arrangement).
// ---------------------------------------------------------------------------
__global__ __launch_bounds__(256) void convB_binA_kernel(
    const float* __restrict__ Wr, uint4* __restrict__ Bp,
    const int* __restrict__ adj_pos, const int* __restrict__ adj_neg,
    int* __restrict__ bucketCount, unsigned int* __restrict__ edges_tmp,
    int N, int E)
{
    __shared__ int hist[512];
    __shared__ int base[512];
    __shared__ int cur[512];
    const int tid = threadIdx.x;

    if ((int)blockIdx.x < 32) {
        // ---- convB role ----
        const int t = blockIdx.x * 256 + tid;
        const int kb  = t >> 8;
        const int col = t & 255;
        const int rel = col >> 7;
        const int cc  = col & 127;
        unsigned short v[8];
        #pragma unroll
        for (int jj = 0; jj < 8; ++jj) {
            const int k = kb * 8 + jj;
            v[jj] = f2bf(Wr[(size_t)rel * 256 * 128 + (size_t)k * 128 + cc]);
        }
        Bp[t] = *reinterpret_cast<const uint4*>(v);
        return;
    }

    // ---- binA role ----
    const int bb = blockIdx.x - 32;
    const long long e0 = (long long)bb * EPB_A;
    const long long twoE = 2LL * E;

    hist[tid] = 0;
    hist[tid + 256] = 0;

    int esrc[EPT_A];
    unsigned int erec[EPT_A];
    #pragma unroll
    for (int k = 0; k < EPT_A; ++k) {
        const long long idx = e0 + (long long)k * 256 + tid;
        if (idx < twoE) {
            const int rel = (idx >= E) ? 1 : 0;
            const long long eidx = rel ? idx - E : idx;
            const int* __restrict__ adj = rel ? adj_neg : adj_pos;
            const int src = adj[eidx];
            const int dst = adj[E + eidx];
            esrc[k] = src;
            erec[k] = (unsigned int)dst | ((unsigned int)rel << 17) |
                      ((unsigned int)(src & (BUCK - 1)) << 18);
        } else {
            esrc[k] = -1;
        }
    }
    __syncthreads();

    #pragma unroll
    for (int k = 0; k < EPT_A; ++k)
        if (esrc[k] >= 0) atomicAdd(&hist[esrc[k] >> BUCK_BITS], 1);
    __syncthreads();

    {
        const int rot = (bb * 61) & 511;
        #pragma unroll
        for (int q = 0; q < 2; ++q) {
            const int t2 = (tid + q * 256 + rot) & 511;
            const int hv = hist[t2];
            base[t2] = hv ? atomicAdd(&bucketCount[t2], hv) : 0;
            cur[t2] = 0;
        }
    }
    __syncthreads();

    #pragma unroll
    for (int k = 0; k < EPT_A; ++k) {
        if (esrc[k] >= 0) {
            const int b = esrc[k] >> BUCK_BITS;
            const int r = atomicAdd(&cur[b], 1);
            const int pos = base[b] + r;
            if (pos < CAP)
                edges_tmp[(size_t)b * CAP + pos] = erec[k];
        }
    }
}

// ---------------------------------------------------------------------------
// Fused MFMA GEMM (r14 structure + r17 fixes):
//  - staging loads HOISTED (all 8 float4 in flight before convert/LDS-write)
//  - 1-deep B + A prefetch across the kc loop (B was 8 dependent L2 loads)
//  - h stored as PACKED uints (ct-pair per uint, permuted col layout):
//      h32[(wn*N+row)*64 + q*16 + cl] = {col 32q+cl, col 32q+16+cl}
//    -> 16 coalesced 4B stores/thread instead of 32 scalar 2B stores.
//    Gather reads the same linear uint index; only out/bias col mapping moves.
// Block = 4 waves (wm = row-half, wn = relation), 32 rows staged, 16KB LDS.
// ---------------------------------------------------------------------------
__global__ __launch_bounds__(256) void mfma_gemm_kernel(
    const float* __restrict__ X, const uint4* __restrict__ Bp,
    const float* __restrict__ ee, const float* __restrict__ a,
    unsigned int* __restrict__ h32, float* __restrict__ sd, int N)
{
    __shared__ unsigned short Alds[32 * 256];   // 16 KB
    const int tid  = threadIdx.x;
    const int lane = tid & 63;
    const int w    = tid >> 6;
    const int wm   = w >> 1;
    const int wn   = w & 1;
    const int cl   = lane & 15;
    const int g    = lane >> 4;
    const int tile0 = blockIdx.x * 32;

    // ---- stage X tile -> LDS bf16 (hoisted loads, XOR swizzle) ----
    {
        float4 fa[4], fb[4];
        #pragma unroll
        for (int pass = 0; pass < 4; ++pass) {
            const int L  = pass * 256 + tid;
            const int r  = L >> 5;
            const int c8 = L & 31;
            const int row = tile0 + r;
            fa[pass] = make_float4(0.f, 0.f, 0.f, 0.f);
            fb[pass] = make_float4(0.f, 0.f, 0.f, 0.f);
            if (row < N) {
                const float* xp = &X[(size_t)row * 256 + c8 * 8];
                fa[pass] = *reinterpret_cast<const float4*>(xp);
                fb[pass] = *reinterpret_cast<const float4*>(xp + 4);
            }
        }
        #pragma unroll
        for (int pass = 0; pass < 4; ++pass) {
            const int L  = pass * 256 + tid;
            const int r  = L >> 5;
            const int c8 = L & 31;
            unsigned short v[8];
            v[0]=f2bf(fa[pass].x); v[1]=f2bf(fa[pass].y);
            v[2]=f2bf(fa[pass].z); v[3]=f2bf(fa[pass].w);
            v[4]=f2bf(fb[pass].x); v[5]=f2bf(fb[pass].y);
            v[6]=f2bf(fb[pass].z); v[7]=f2bf(fb[pass].w);
            const int su = c8 ^ (r & 7);
            *reinterpret_cast<bf16x8*>(&Alds[r * 256 + su * 8]) =
                *reinterpret_cast<const bf16x8*>(v);
        }
    }
    __syncthreads();

    // ---- MFMA loop with 1-deep B/A prefetch ----
    f32x4 acc[8];
    #pragma unroll
    for (int ct = 0; ct < 8; ++ct)
        acc[ct] = (f32x4){0.f, 0.f, 0.f, 0.f};

    const int rl = wm * 16 + cl;            // local A row
    bf16x8 bcur[8], acur;
    {
        const int ku = g;                   // kc = 0
        #pragma unroll
        for (int ct = 0; ct < 8; ++ct) {
            const int col = wn * 128 + ct * 16 + cl;
            bcur[ct] = *reinterpret_cast<const bf16x8*>(Bp + ku * 256 + col);
        }
        acur = *reinterpret_cast<const bf16x8*>(
            &Alds[rl * 256 + (ku ^ (rl & 7)) * 8]);
    }
    #pragma unroll
    for (int kc = 0; kc < 8; ++kc) {
        bf16x8 bnext[8], anext;
        if (kc < 7) {
            const int ku = (kc + 1) * 4 + g;
            #pragma unroll
            for (int ct = 0; ct < 8; ++ct) {
                const int col = wn * 128 + ct * 16 + cl;
                bnext[ct] = *reinterpret_cast<const bf16x8*>(Bp + ku * 256 + col);
            }
            anext = *reinterpret_cast<const bf16x8*>(
                &Alds[rl * 256 + (ku ^ (rl & 7)) * 8]);
        }
        #pragma unroll
        for (int ct = 0; ct < 8; ++ct)
            acc[ct] = __builtin_amdgcn_mfma_f32_16x16x32_bf16(
                acur, bcur[ct], acc[ct], 0, 0, 0);
        if (kc < 7) {
            #pragma unroll
            for (int ct = 0; ct < 8; ++ct) bcur[ct] = bnext[ct];
            acur = anext;
        }
    }

    // ---- epilogue: ee scale, packed h store, fused s/d dots ----
    const int rt = blockIdx.x * 2 + wm;
    float eev[8], asv[8], adv[8];
    #pragma unroll
    for (int ct = 0; ct < 8; ++ct) {
        const int col = wn * 128 + ct * 16 + cl;
        const int cc  = col & 127;
        eev[ct] = ee[col];
        asv[ct] = a[cc];
        adv[ct] = a[128 + cc];
    }

    float s_acc[4], d_acc[4];
    #pragma unroll
    for (int reg = 0; reg < 4; ++reg) {
        const int row = rt * 16 + g * 4 + reg;
        const bool ok = row < N;
        float sp = 0.f, dp = 0.f;
        float vv[8];
        #pragma unroll
        for (int ct = 0; ct < 8; ++ct) {
            vv[ct] = acc[ct][reg] * eev[ct];
            sp += vv[ct] * asv[ct];
            dp += vv[ct] * adv[ct];
        }
        if (ok) {
            #pragma unroll
            for (int q = 0; q < 4; ++q) {
                const unsigned int u =
                    (unsigned int)f2bf(vv[2 * q]) |
                    ((unsigned int)f2bf(vv[2 * q + 1]) << 16);
                h32[((size_t)wn * N + row) * 64 + q * 16 + cl] = u;
            }
        }
        s_acc[reg] = sp;
        d_acc[reg] = dp;
    }
    #pragma unroll
    for (int reg = 0; reg < 4; ++reg) {
        float sp = s_acc[reg], dp = d_acc[reg];
        #pragma unroll
        for (int off = 1; off < 16; off <<= 1) {
            sp += __shfl_xor(sp, off);
            dp += __shfl_xor(dp, off);
        }
        if (cl == 0) {
            const int row = rt * 16 + g * 4 + reg;
            if (row < N) {
                sd[(size_t)wn * 2 * N + row]     = sp;
                sd[(size_t)wn * 2 * N + N + row] = dp;
            }
        }
    }
}

// ---------------------------------------------------------------------------
// sortB: one 512-thread block per bucket — unchanged from r14.
// ---------------------------------------------------------------------------
__global__ __launch_bounds__(512) void sortB_kernel(
    const int* __restrict__ bucketCount, const unsigned int* __restrict__ edges_tmp,
    const float* __restrict__ sd,
    uint2* __restrict__ edges_final,
    int* __restrict__ rowBeg, int* __restrict__ rowEnd,
    float* __restrict__ rowSum, int N)
{
    __shared__ int hist[BUCK];
    __shared__ int cur[BUCK];
    __shared__ int ssum[BUCK];
    __shared__ float sSrc[2][BUCK];
    __shared__ float rsLds[BUCK];
    const int tid = threadIdx.x;          // 0..511
    const int b   = blockIdx.x;
    const int s0  = b << BUCK_BITS;
    const size_t tb = (size_t)b * CAP;
    const int cnt = min(bucketCount[b], CAP);

    if (tid < BUCK) {
        hist[tid] = 0;
        rsLds[tid] = 0.f;
        const int gsrc = s0 + tid;
        sSrc[0][tid] = (gsrc < N) ? sd[gsrc] : 0.f;
        sSrc[1][tid] = (gsrc < N) ? sd[2 * (size_t)N + gsrc] : 0.f;
    }
    __syncthreads();
    for (int j = tid; j < cnt; j += 512)
        atomicAdd(&hist[edges_tmp[tb + j] >> 18], 1);
    __syncthreads();

    int h0 = 0, incl = 0;
    if (tid < BUCK) { h0 = hist[tid]; ssum[tid] = h0; incl = h0; }
    __syncthreads();
    for (int off = 1; off < BUCK; off <<= 1) {
        const int u = (tid < BUCK && tid >= off) ? ssum[tid - off] : 0;
        __syncthreads();
        if (tid < BUCK) { incl += u; ssum[tid] = incl; }
        __syncthreads();
    }
    if (tid < BUCK) {
        const int excl = incl - h0;
        cur[tid] = excl;
        const int gidx = s0 + tid;
        if (gidx < N) {
            rowBeg[gidx] = (int)tb + excl;
            rowEnd[gidx] = (int)tb + incl;
        }
    }
    __syncthreads();
    for (int j = tid; j < cnt; j += 512) {
        const unsigned int r = edges_tmp[tb + j];
        const int sl  = r >> 18;
        const int rel = (r >> 17) & 1;
        const int dst = r & 0x1FFFF;
        float z = sSrc[rel][sl] + sd[(size_t)rel * 2 * N + N + dst];
        z = z > 0.f ? z : ALPHA * z;
        const float ev = 1.f / (1.f + __expf(-z));
        const int pos = atomicAdd(&cur[sl], 1);
        atomicAdd(&rsLds[sl], ev);
        edges_final[tb + pos] =
            make_uint2((unsigned int)(rel * N + dst), __float_as_uint(ev));
    }
    __syncthreads();
    if (tid < BUCK) {
        const int gidx = s0 + tid;
        if (gidx < N) rowSum[gidx] = rsLds[tid];
    }
}

// ---------------------------------------------------------------------------
// Gather: one wave per node; 8-deep unrolled; h-read address UNCHANGED
// (linear uint index lane); only out/bias col mapping follows the packed
// h layout: lane (q=lane>>4, cl=lane&15) -> cols 32q+cl and 32q+16+cl.
// ---------------------------------------------------------------------------
__global__ __launch_bounds__(256) void gather_kernel(
    const int* __restrict__ rowBeg, const int* __restrict__ rowEnd,
    const float* __restrict__ rowSum,
    const uint2* __restrict__ edges,
    const unsigned int* __restrict__ h32,
    const float* __restrict__ bias, float* __restrict__ out, int N)
{
    const long long gw = ((long long)blockIdx.x * blockDim.x + threadIdx.x) >> 6;
    const int lane = threadIdx.x & 63;
    if (gw >= N) return;
    const int n = (int)gw;

    const int beg = rowBeg[n];
    const int end = rowEnd[n];
    const unsigned loff = (unsigned)(lane << 2);
    const char* __restrict__ hb = (const char*)h32;

    float ax = 0.f, ay = 0.f;
    int j = beg;
    for (; j + 8 <= end; j += 8) {
        uint2 r[8];
        #pragma unroll
        for (int k = 0; k < 8; ++k) r[k] = edges[j + k];
        unsigned int hv[8];
        #pragma unroll
        for (int k = 0; k < 8; ++k)
            hv[k] = *reinterpret_cast<const unsigned int*>(
                hb + ((r[k].x << 8) + loff));
        #pragma unroll
        for (int k = 0; k < 8; ++k) {
            const float e = __uint_as_float(r[k].y);
            ax += e * bflo(hv[k]);
            ay += e * bfhi(hv[k]);
        }
    }
    for (; j + 4 <= end; j += 4) {
        uint2 r[4];
        #pragma unroll
        for (int k = 0; k < 4; ++k) r[k] = edges[j + k];
        unsigned int hv[4];
        #pragma unroll
        for (int k = 0; k < 4; ++k)
            hv[k] = *reinterpret_cast<const unsigned int*>(
                hb + ((r[k].x << 8) + loff));
        #pragma unroll
        for (int k = 0; k < 4; ++k) {
            const float e = __uint_as_float(r[k].y);
            ax += e * bflo(hv[k]);
            ay += e * bfhi(hv[k]);
        }
    }
    for (; j < end; ++j) {
        const uint2 r = edges[j];
        const unsigned int hv = *reinterpret_cast<const unsigned int*>(
            hb + ((r.x << 8) + loff));
        const float e = __uint_as_float(r.y);
        ax += e * bflo(hv);
        ay += e * bfhi(hv);
    }
    const float inv = 1.f / (rowSum[n] + EPSV);
    const int q  = lane >> 4;
    const int cl = lane & 15;
    const int c0 = q * 32 + cl;
    const int c1 = c0 + 16;
    out[(size_t)n * 128 + c0] = ax * inv + bias[c0];
    out[(size_t)n * 128 + c1] = ay * inv + bias[c1];
}

extern "C" void kernel_launch(void* const* d_in, const int* in_sizes, int n_in,
                              void* d_out, int out_size, void* d_ws, size_t ws_size,
                              hipStream_t stream) {
    const float* X      = (const float*)d_in[0];   // N x 256
    const float* ee     = (const float*)d_in[1];   // 2 x 128
    const float* Wr     = (const float*)d_in[2];   // 2 x 256 x 128
    const float* a      = (const float*)d_in[3];   // 1 x 256
    const float* bias   = (const float*)d_in[4];   // 1 x 128
    const int* adj_pos  = (const int*)d_in[5];     // 2 x E
    const int* adj_neg  = (const int*)d_in[6];     // 2 x E

    const int N = in_sizes[0] / 256;
    const int E = in_sizes[5] / 2;
    const int twoE = 2 * E;
    float* out = (float*)d_out;

    const int gemmBlocks = (N + 31) / 32;
    const int NBUCK = (N + BUCK - 1) >> BUCK_BITS;
    const int binBlocks = (twoE + EPB_A - 1) / EPB_A;

    // workspace layout
    char* ws = (char*)d_ws;
    uint4* Bp = (uint4*)ws;
    char* p = ws + 32 * 256 * 16;                               // 128 KB
    unsigned int* h32 = (unsigned int*)p; p += (size_t)2 * N * 64 * 4; // 51.2 MB
    float* sd         = (float*)p;  p += (size_t)4 * N * 4;
    int* bucketCount  = (int*)p;    p += 512 * 4;
    int* rowBeg       = (int*)p;    p += (size_t)N * 4;
    int* rowEnd       = (int*)p;    p += (size_t)N * 4;
    float* rowSum     = (float*)p;  p += (size_t)N * 4;
    p = (char*)(((uintptr_t)p + 15) & ~(uintptr_t)15);
    unsigned int* edges_tmp = (unsigned int*)p; p += (size_t)NBUCK * CAP * 4; // 8 MB
    uint2* edges_final = (uint2*)p; p += (size_t)NBUCK * CAP * 8;            // 16 MB

    (void)hipMemsetAsync(bucketCount, 0, 512 * sizeof(int), stream);

    convB_binA_kernel<<<32 + binBlocks, 256, 0, stream>>>(
        Wr, Bp, adj_pos, adj_neg, bucketCount, edges_tmp, N, E);

    mfma_gemm_kernel<<<gemmBlocks, 256, 0, stream>>>(X, Bp, ee, a, h32, sd, N);

    sortB_kernel<<<NBUCK, 512, 0, stream>>>(
        bucketCount, edges_tmp, sd, edges_final, rowBeg, rowEnd, rowSum, N);

    gather_kernel<<<(int)(((long long)N * 64 + 255) / 256), 256, 0, stream>>>(
        rowBeg, rowEnd, rowSum, edges_final, h32, bias, out, N);
}